// Round 3
// baseline (565.174 us; speedup 1.0000x reference)
//
#include <hip/hip_runtime.h>
#include <stdint.h>

// Problem constants: B=32, N=1024, IN=64, ATTN=128, OUT=64, H=4, dh=32
typedef __attribute__((ext_vector_type(4))) float f32x4;
typedef __attribute__((ext_vector_type(4))) unsigned int u32x4;
typedef __attribute__((ext_vector_type(2))) unsigned int u32x2;
typedef __attribute__((ext_vector_type(8))) short bf16x8;

__device__ __forceinline__ unsigned short f2bf(float f) {
    union { float f; unsigned int u; } c; c.f = f;
    unsigned int u = c.u;
    unsigned int r = (u + 0x7FFFu + ((u >> 16) & 1u)) >> 16;  // RNE
    return (unsigned short)r;
}
__device__ __forceinline__ float bf2f(unsigned short h) {
    union { unsigned int u; float f; } c; c.u = ((unsigned int)h) << 16;
    return c.f;
}
// branch-free tanh: saturates correctly at +/-inf
__device__ __forceinline__ float tanh_fast(float x) {
    float t = __expf(2.0f * x);
    return 1.0f - 2.0f * __builtin_amdgcn_rcpf(t + 1.0f);
}

// ---------------- kernel A: degrees d = rsqrt(max(rowsum(adj'),1)) -------------
__global__ __launch_bounds__(256) void k_deg(const float* __restrict__ adj,
                                             float* __restrict__ dvec) {
    int wid = threadIdx.x >> 6, l = threadIdx.x & 63;
    int row = blockIdx.x * 4 + wid;          // 0..32767
    int b = row >> 10, i = row & 1023;
    const float* rp = adj + ((size_t)b << 20) + ((size_t)i << 10);
    float s = 0.f;
#pragma unroll
    for (int it = 0; it < 4; ++it) {
        f32x4 v = *(const f32x4*)(rp + it * 256 + l * 4);
        s += v.x + v.y + v.z + v.w;
    }
#pragma unroll
    for (int m = 32; m >= 1; m >>= 1) s += __shfl_xor(s, m);
    if (l == 0) {
        float diag = rp[i];
        float S = s - diag + 1.0f;     // diagonal replaced by 1
        S = fmaxf(S, 1.0f);
        dvec[(b << 10) + i] = 1.0f / sqrtf(S);
    }
}

// ------ kernel B: xsT[b][c][j] = bf16(d_j * x[b][j][c]); block 512 = W prep ----
__global__ __launch_bounds__(256) void k_xs(const float* __restrict__ x,
                                            const float* __restrict__ dvec,
                                            unsigned short* __restrict__ xsT,
                                            const float* __restrict__ Wq,
                                            const float* __restrict__ Wk,
                                            const float* __restrict__ Wv,
                                            const float* __restrict__ bq,
                                            const float* __restrict__ bk,
                                            const float* __restrict__ bv,
                                            unsigned short* __restrict__ WThiG,
                                            unsigned short* __restrict__ WTloG,
                                            float* __restrict__ biasG) {
    __shared__ float Lt[64][65];
    int tid = threadIdx.x;
    if (blockIdx.x == 512) {   // W hi/lo split prep: WT[320][64] (c-major)
        for (int idx = tid; idx < 8192; idx += 256) {
            int k = idx >> 7, c = idx & 127;
            float w = Wq[idx]; unsigned short h = f2bf(w);
            WThiG[(c << 6) + k] = h; WTloG[(c << 6) + k] = f2bf(w - bf2f(h));
        }
        for (int idx = tid; idx < 8192; idx += 256) {
            int k = idx >> 7, c = idx & 127;
            float w = Wk[idx]; unsigned short h = f2bf(w);
            WThiG[((128 + c) << 6) + k] = h; WTloG[((128 + c) << 6) + k] = f2bf(w - bf2f(h));
        }
        for (int idx = tid; idx < 4096; idx += 256) {
            int k = idx >> 6, c = idx & 63;
            float w = Wv[idx]; unsigned short h = f2bf(w);
            WThiG[((256 + c) << 6) + k] = h; WTloG[((256 + c) << 6) + k] = f2bf(w - bf2f(h));
        }
        for (int e = tid; e < 320; e += 256)
            biasG[e] = (e < 128) ? bq[e] : ((e < 256) ? bk[e - 128] : bv[e - 256]);
        return;
    }
    int b = blockIdx.x >> 4, j0 = (blockIdx.x & 15) << 6;
    {
        int r = tid >> 2, cseg = (tid & 3) << 4;
        float dj = dvec[(b << 10) + j0 + r];
        const float* xr = x + (((size_t)((b << 10) + j0 + r)) << 6) + cseg;
#pragma unroll
        for (int q = 0; q < 4; ++q) {
            f32x4 v = *(const f32x4*)(xr + (q << 2));
#pragma unroll
            for (int e = 0; e < 4; ++e) Lt[r][cseg + (q << 2) + e] = v[e] * dj;
        }
    }
    __syncthreads();
    {
        int c = tid >> 2, js = (tid & 3) << 4;
        unsigned int pk[8];
#pragma unroll
        for (int e = 0; e < 8; ++e) {
            unsigned short lo16 = f2bf(Lt[js + 2 * e][c]);
            unsigned short hi16 = f2bf(Lt[js + 2 * e + 1][c]);
            pk[e] = (unsigned)lo16 | ((unsigned)hi16 << 16);
        }
        unsigned short* op = xsT + ((size_t)b << 16) + ((size_t)c << 10) + j0 + js;
        u32x4 w0 = {pk[0], pk[1], pk[2], pk[3]};
        u32x4 w1 = {pk[4], pk[5], pk[6], pk[7]};
        *(u32x4*)op = w0;
        *(u32x4*)(op + 8) = w1;
    }
}

// ---------------- kernel C: Mg[i][c] = d_i * sum_j adj'[i][j] * xs[j][c] -------
#define APAD 72   // LDS row stride (bf16 elems)
__global__ __launch_bounds__(256) void k_m(const float* __restrict__ adj,
                                           const unsigned short* __restrict__ xsT,
                                           const float* __restrict__ dvec,
                                           float* __restrict__ Mg) {
    __shared__ unsigned short Al[32][APAD];
    __shared__ unsigned short Bl[64][APAD];
    int bid = blockIdx.x;
    int xcd = bid & 7, t2 = bid >> 3;
    int bg = t2 >> 5, mt = t2 & 31;
    int b = (bg << 3) + xcd;
    int i0 = mt << 5;
    int tid = threadIdx.x;
    int wid = tid >> 6, l = tid & 63;
    int wm = wid >> 1, wn = wid & 1;
    int lr = l & 15, lg = l >> 4;

    f32x4 acc[2];
    acc[0] = (f32x4){0.f, 0.f, 0.f, 0.f};
    acc[1] = (f32x4){0.f, 0.f, 0.f, 0.f};

    const float* adjB = adj + ((size_t)b << 20);
    const unsigned short* xsB = xsT + ((size_t)b << 16);
    int ar0 = tid >> 4;            // 0..15
    int ac4 = (tid & 15) << 2;     // 0..60

    for (int kt = 0; kt < 16; ++kt) {
        int j0 = kt << 6;
        __syncthreads();
#pragma unroll
        for (int rr = 0; rr < 2; ++rr) {
            int row = ar0 + (rr << 4);
            int gi  = i0 + row;
            f32x4 v = *(const f32x4*)(adjB + ((size_t)gi << 10) + j0 + ac4);
            int gj = j0 + ac4;
            if (gj + 0 == gi) v.x = 1.0f;
            if (gj + 1 == gi) v.y = 1.0f;
            if (gj + 2 == gi) v.z = 1.0f;
            if (gj + 3 == gi) v.w = 1.0f;
            u32x2 pk;
            pk.x = (unsigned)f2bf(v.x) | ((unsigned)f2bf(v.y) << 16);
            pk.y = (unsigned)f2bf(v.z) | ((unsigned)f2bf(v.w) << 16);
            *(u32x2*)&Al[row][ac4] = pk;
        }
#pragma unroll
        for (int rep = 0; rep < 2; ++rep) {
            int idx = (rep << 8) + tid;
            int crow = idx >> 3, ch = (idx & 7) << 3;
            u32x4 v = *(const u32x4*)(xsB + ((size_t)crow << 10) + j0 + ch);
            *(u32x4*)&Bl[crow][ch] = v;
        }
        __syncthreads();
#pragma unroll
        for (int kk = 0; kk < 2; ++kk) {
            bf16x8 av = *(const bf16x8*)&Al[wm * 16 + lr][kk * 32 + lg * 8];
            bf16x8 b0 = *(const bf16x8*)&Bl[wn * 32 + lr][kk * 32 + lg * 8];
            bf16x8 b1 = *(const bf16x8*)&Bl[wn * 32 + 16 + lr][kk * 32 + lg * 8];
            acc[0] = __builtin_amdgcn_mfma_f32_16x16x32_bf16(av, b0, acc[0], 0, 0, 0);
            acc[1] = __builtin_amdgcn_mfma_f32_16x16x32_bf16(av, b1, acc[1], 0, 0, 0);
        }
    }
#pragma unroll
    for (int r = 0; r < 4; ++r) {
        int gi = i0 + wm * 16 + lg * 4 + r;
        float dv = dvec[(b << 10) + gi];
#pragma unroll
        for (int ni = 0; ni < 2; ++ni) {
            int cg = wn * 32 + ni * 16 + lr;
            Mg[(((size_t)((b << 10) + gi)) << 6) + cg] = dv * acc[ni][r];
        }
    }
}

// -------- kernel D: [QKV] = Mg @ W + bias (hi/lo MFMA); W pre-split in ws ------
__global__ __launch_bounds__(256) void k_qkv(const float* __restrict__ Mg,
                                             const unsigned short* __restrict__ WThiG,
                                             const unsigned short* __restrict__ WTloG,
                                             const float* __restrict__ biasG,
                                             unsigned short* __restrict__ QKhi,
                                             unsigned short* __restrict__ QKlo,
                                             float* __restrict__ outV) {
    __shared__ unsigned short WThi[320][72];
    __shared__ unsigned short WTlo[320][72];
    __shared__ float biasl[320];
    int tid = threadIdx.x;
#pragma unroll
    for (int it = 0; it < 10; ++it) {
        int idx = (it << 8) + tid;          // 0..2559 (20480 shorts / 8)
        int row = idx >> 3, cs = (idx & 7) << 3;
        *(u32x4*)&WThi[row][cs] = *(const u32x4*)(WThiG + (row << 6) + cs);
        *(u32x4*)&WTlo[row][cs] = *(const u32x4*)(WTloG + (row << 6) + cs);
    }
    for (int e = tid; e < 320; e += 256) biasl[e] = biasG[e];

    int wid = tid >> 6, l = tid & 63, lr = l & 15, lg = l >> 4;
    int gr0 = (blockIdx.x << 6) + (wid << 4);
    const float* mrow = Mg + (((size_t)(gr0 + lr)) << 6);
    bf16x8 ahi[2], alo[2];
#pragma unroll
    for (int kk = 0; kk < 2; ++kk) {
        f32x4 v0 = *(const f32x4*)(mrow + kk * 32 + lg * 8);
        f32x4 v1 = *(const f32x4*)(mrow + kk * 32 + lg * 8 + 4);
#pragma unroll
        for (int e = 0; e < 8; ++e) {
            float f = (e < 4) ? v0[e] : v1[e - 4];
            unsigned short h = f2bf(f);
            ahi[kk][e] = (short)h;
            alo[kk][e] = (short)f2bf(f - bf2f(h));
        }
    }
    __syncthreads();

    f32x4 acc[20];
#pragma unroll
    for (int n = 0; n < 20; ++n) acc[n] = (f32x4){0.f, 0.f, 0.f, 0.f};
#pragma unroll
    for (int n = 0; n < 20; ++n) {
#pragma unroll
        for (int kk = 0; kk < 2; ++kk) {
            bf16x8 bh = *(const bf16x8*)&WThi[n * 16 + lr][kk * 32 + lg * 8];
            bf16x8 bl = *(const bf16x8*)&WTlo[n * 16 + lr][kk * 32 + lg * 8];
            acc[n] = __builtin_amdgcn_mfma_f32_16x16x32_bf16(ahi[kk], bh, acc[n], 0, 0, 0);
            acc[n] = __builtin_amdgcn_mfma_f32_16x16x32_bf16(ahi[kk], bl, acc[n], 0, 0, 0);
            acc[n] = __builtin_amdgcn_mfma_f32_16x16x32_bf16(alo[kk], bh, acc[n], 0, 0, 0);
        }
    }
#pragma unroll
    for (int n = 0; n < 20; ++n) {
        int c = n * 16 + lr;
        float bias = biasl[c];
#pragma unroll
        for (int r = 0; r < 4; ++r) {
            int gr = gr0 + lg * 4 + r;
            float val = acc[n][r] + bias;
            if (n < 16) {
                size_t base = ((size_t)gr << 8) + c;
                unsigned short h = f2bf(val);
                QKhi[base] = h;
                QKlo[base] = f2bf(val - bf2f(h));
            } else {
                outV[((size_t)gr << 6) + (c - 256)] = val;
            }
        }
    }
}

// -------- kernel E: A = sym(mean_h tanh(QK^T/8)) — register head-reduction -----
// dir0: mfma(Q_I,K_J) -> S[i,j]; dir1: mfma(K_I,Q_J) -> S[j,i] in SAME C layout.
__global__ __launch_bounds__(256) void k_attn(const unsigned short* __restrict__ QKhi,
                                              const unsigned short* __restrict__ QKlo,
                                              float* __restrict__ Aout) {
    __shared__ float As[32][36];
    int bid = blockIdx.x;
    int xcd = bid & 7, t2 = bid >> 3;
    int bg = t2 / 528, pr = t2 - bg * 528;
    int b  = (bg << 3) + xcd;
    int ti = 0;
    { int p = pr; while (p >= (32 - ti)) { p -= (32 - ti); ++ti; } pr = p; }
    int tj = ti + pr;
    bool diag = (ti == tj);
    int qi0 = ti << 5, qj0 = tj << 5;
    int tid = threadIdx.x;
    int wid = tid >> 6, l = tid & 63;
    int wm = wid >> 1, wn = wid & 1;
    int lr = l & 15, lg = l >> 4, ko = lg << 3;
    const unsigned short* hiB = QKhi + ((size_t)b << 18);
    const unsigned short* loB = QKlo + ((size_t)b << 18);
    size_t offI = ((size_t)(qi0 + wm * 16 + lr) << 8) + ko;   // I rows (A-operands)
    size_t offJ = ((size_t)(qj0 + wn * 16 + lr) << 8) + ko;   // J rows (B-operands)

    bf16x8 qih[4], qil[4], kih[4], kil[4], kjh[4], kjl[4], qjh[4], qjl[4];
#pragma unroll
    for (int h = 0; h < 4; ++h) {
        int hq = h << 5;            // Q col block
        int hk = 128 + (h << 5);    // K col block
        qih[h] = *(const bf16x8*)(hiB + offI + hq);
        qil[h] = *(const bf16x8*)(loB + offI + hq);
        kih[h] = *(const bf16x8*)(hiB + offI + hk);
        kil[h] = *(const bf16x8*)(loB + offI + hk);
        kjh[h] = *(const bf16x8*)(hiB + offJ + hk);
        kjl[h] = *(const bf16x8*)(loB + offJ + hk);
        qjh[h] = *(const bf16x8*)(hiB + offJ + hq);
        qjl[h] = *(const bf16x8*)(loB + offJ + hq);
    }
    f32x4 asum = {0.f, 0.f, 0.f, 0.f};
#pragma unroll
    for (int h = 0; h < 4; ++h) {
        f32x4 s0 = {0.f, 0.f, 0.f, 0.f}, s1 = {0.f, 0.f, 0.f, 0.f};
        s0 = __builtin_amdgcn_mfma_f32_16x16x32_bf16(qih[h], kjh[h], s0, 0, 0, 0);
        s0 = __builtin_amdgcn_mfma_f32_16x16x32_bf16(qih[h], kjl[h], s0, 0, 0, 0);
        s0 = __builtin_amdgcn_mfma_f32_16x16x32_bf16(qil[h], kjh[h], s0, 0, 0, 0);
        s1 = __builtin_amdgcn_mfma_f32_16x16x32_bf16(kih[h], qjh[h], s1, 0, 0, 0);
        s1 = __builtin_amdgcn_mfma_f32_16x16x32_bf16(kih[h], qjl[h], s1, 0, 0, 0);
        s1 = __builtin_amdgcn_mfma_f32_16x16x32_bf16(kil[h], qjh[h], s1, 0, 0, 0);
#pragma unroll
        for (int r = 0; r < 4; ++r)
            asum[r] += tanh_fast(s0[r] * 0.125f) + tanh_fast(s1[r] * 0.125f);
    }
    // stage block tile (scaled) to LDS
#pragma unroll
    for (int r = 0; r < 4; ++r)
        As[wm * 16 + (lg << 2) + r][wn * 16 + lr] = asum[r] * 0.125f;
    __syncthreads();
    int row = tid >> 3, c4 = (tid & 7) << 2;
    f32x4 v;
#pragma unroll
    for (int e = 0; e < 4; ++e) v[e] = As[row][c4 + e];
    *(f32x4*)(Aout + ((size_t)b << 20) + ((size_t)(qi0 + row) << 10) + qj0 + c4) = v;
    if (!diag) {
        f32x4 w2;
#pragma unroll
        for (int e = 0; e < 4; ++e) w2[e] = As[c4 + e][row];
        *(f32x4*)(Aout + ((size_t)b << 20) + ((size_t)(qj0 + row) << 10) + qi0 + c4) = w2;
    }
}

extern "C" void kernel_launch(void* const* d_in, const int* in_sizes, int n_in,
                              void* d_out, int out_size, void* d_ws, size_t ws_size,
                              hipStream_t stream) {
    const float* x   = (const float*)d_in[0];
    const float* adj = (const float*)d_in[1];
    // d_in[2] = flags (unused by reference forward)
    const float* Wq = (const float*)d_in[3];
    const float* bq = (const float*)d_in[4];
    const float* Wk = (const float*)d_in[5];
    const float* bk = (const float*)d_in[6];
    const float* Wv = (const float*)d_in[7];
    const float* bv = (const float*)d_in[8];

    float* out  = (float*)d_out;
    float* outV = out;                 // [32,1024,64]
    float* Aout = out + 2097152;       // [32,1024,1024]

    char* ws = (char*)d_ws;
    float*          dvec  = (float*)ws;                                   // 128 KiB
    unsigned short* xsT   = (unsigned short*)(ws + 131072);               // 4 MiB
    float*          Mg    = (float*)(ws + 4325376);                       // 8 MiB
    unsigned short* QKhi  = (unsigned short*)(ws + 12713984);             // 16 MiB
    unsigned short* QKlo  = (unsigned short*)(ws + 29491200);             // 16 MiB
    unsigned short* WThiG = (unsigned short*)(ws + 46268416);             // 40 KiB
    unsigned short* WTloG = (unsigned short*)(ws + 46309376);             // 40 KiB
    float*          biasG = (float*)(ws + 46350336);                      // 1.25 KiB

    hipLaunchKernelGGL(k_deg,  dim3(8192),  dim3(256), 0, stream, adj, dvec);
    hipLaunchKernelGGL(k_xs,   dim3(513),   dim3(256), 0, stream, x, dvec, xsT,
                       Wq, Wk, Wv, bq, bk, bv, WThiG, WTloG, biasG);
    hipLaunchKernelGGL(k_m,    dim3(1024),  dim3(256), 0, stream, adj, xsT, dvec, Mg);
    hipLaunchKernelGGL(k_qkv,  dim3(512),   dim3(256), 0, stream, Mg, WThiG, WTloG,
                       biasG, QKhi, QKlo, outV);
    hipLaunchKernelGGL(k_attn, dim3(16896), dim3(256), 0, stream, QKhi, QKlo, Aout);
}